// Round 8
// baseline (19574.159 us; speedup 1.0000x reference)
//
#include <hip/hip_runtime.h>
#include <hip/hip_runtime_api.h>
#include <hip/hip_fp16.h>
#include <math.h>

// ESN: x_{t+1} = tanh(w_in * u_t + W @ x_t);  out[t-200] = dot(w_eff, x_{t+1})
//
// R8 = R5 structure (tag16|fp16 self-validating words, relaxed agent atomics,
//      two barriers/step, shfl reduction, coalesced publish by wave 0, fixed
//      16-group ELL) with ONE change: 512 blocks at 2 blocks/CU.
//      Each block: 8 rows, 2 waves/row (8 ELL groups per wave). While one
//      block waits on polls, the co-resident block computes -> latency hiding.

#define Nn 4096
#define WASHOUT_N 200
#define NBLOCKS 512
#define TPB 1024
#define ROWS_PER_BLOCK 8    // Nn / NBLOCKS
#define NWAVES 16           // TPB / 64
#define ELL_CAP 1024        // 16 gather groups x 64 lanes; mean nnz 819

typedef unsigned long long u64t;
typedef unsigned int u32t;

static __device__ __forceinline__ unsigned short f2h(float f) {
    __half h = __float2half_rn(f);
    union { __half h; unsigned short u; } cv; cv.h = h; return cv.u;
}
static __device__ __forceinline__ float h2f(unsigned short ub) {
    union { __half h; unsigned short u; } cv; cv.u = ub; return __half2float(cv.h);
}

__global__ __launch_bounds__(256) void esn_init(
    const float* __restrict__ w_out, const int* __restrict__ mask,
    u32t* __restrict__ xp_a, u32t* __restrict__ xp_b,
    float* __restrict__ w_eff, float* __restrict__ out, int out_n)
{
    int i = blockIdx.x * blockDim.x + threadIdx.x;
    if (i < Nn) {
        xp_a[i] = 0u;            // tag 0 | fp16(0.0) == x_0
        xp_b[i] = 0xFFFF0000u;   // invalid tag (never matches 1..4096)
        w_eff[mask[i]] = w_out[i];
        if (i < out_n) out[i] = 0.0f;
    }
}

// One block per row. Deal nonzeros into 16 gather-groups; each group is one
// wave-wide LDS gather. Keep <=2 cols per LDS bank per group (2-way is free).
__global__ __launch_bounds__(256) void build_ell(
    const float* __restrict__ W, float* __restrict__ ev,
    unsigned short* __restrict__ ec)
{
    int row = blockIdx.x;
    __shared__ unsigned int bank_cnt[32];
    __shared__ unsigned int group_cnt[16];
    if (threadIdx.x < 32) bank_cnt[threadIdx.x] = 0u;
    if (threadIdx.x < 16) group_cnt[threadIdx.x] = 0u;
    __syncthreads();

    const float* wr = W + (size_t)row * Nn;
    size_t base = (size_t)row * ELL_CAP;

    for (int s = threadIdx.x; s < ELL_CAP; s += 256) {
        ev[base + s] = 0.0f;
        ec[base + s] = 0;               // col 0 -> broadcast, free
    }
    __syncthreads();

    for (int j = threadIdx.x; j < Nn; j += 256) {
        float v = wr[j];
        if (v != 0.0f) {
            unsigned int b  = (unsigned int)j & 31u;
            unsigned int jb = atomicAdd(&bank_cnt[b], 1u);
            unsigned int g  = jb & 15u;
            unsigned int s  = 0xFFFFFFFFu;
            for (int tries = 0; tries < 16; ++tries) {
                unsigned int cand = atomicAdd(&group_cnt[g], 1u);
                if (cand < 64u) { s = cand; break; }
                g = (g + 1u) & 15u;
            }
            if (s != 0xFFFFFFFFu) {
                unsigned int i = g >> 2, k = g & 3u;   // g = i*4 + k
                unsigned int pos = 4u * (i * 64u + s) + k;
                ev[base + pos] = v;
                ec[base + pos] = (unsigned short)j;
            }
        }
    }
}

__device__ __forceinline__ u64t xload64(const u64t* p) {
    return __hip_atomic_load(p, __ATOMIC_RELAXED, __HIP_MEMORY_SCOPE_AGENT);
}

__global__ __launch_bounds__(TPB, 8) void esn_step_sparse(
    const float* __restrict__ u, const float* __restrict__ w_in,
    const float* __restrict__ ev, const unsigned short* __restrict__ ec,
    u32t* xp_a, u32t* xp_b, const float* __restrict__ w_eff,
    unsigned short* __restrict__ hist, float* __restrict__ out, int T)
{
    __shared__ __align__(16) float xs[Nn];
    __shared__ float hpart[NWAVES];     // per-wave half-row partial sums
    __shared__ float dpart[NWAVES];

    const int tid  = threadIdx.x;
    const int lane = tid & 63;
    const int wave = tid >> 6;
    const int base_row = blockIdx.x * ROWS_PER_BLOCK;
    const int row  = base_row + (wave >> 1);   // 2 waves per row
    const int half = wave & 1;                 // which 8-group half of the row

    // publisher-side row constants (wave 0, lanes 0..7)
    const float wi_pub = (lane < ROWS_PER_BLOCK) ? w_in[base_row + lane] : 0.0f;
    // fallback-dot weights (no-hist path only)
    const float we0 = w_eff[tid];
    const float we1 = w_eff[TPB + tid];
    const float we2 = w_eff[2 * TPB + tid];
    const float we3 = w_eff[3 * TPB + tid];

    // hoist this wave's half of the row's ELL slice into registers
    // half h covers groups g in [8h, 8h+8) = i in {2h, 2h+1}, all k
    const float4*  v4 = (const float4*)(ev + (size_t)row * ELL_CAP);
    const ushort4* c4 = (const ushort4*)(ec + (size_t)row * ELL_CAP);
    const int i0 = half * 2, i1 = half * 2 + 1;
    const float4  rv0 = v4[i0 * 64 + lane], rv1 = v4[i1 * 64 + lane];
    const ushort4 rc0 = c4[i0 * 64 + lane], rc1 = c4[i1 * 64 + lane];

    u32t* bufs[2] = { xp_a, xp_b };
    const bool have_hist = (hist != nullptr);

    for (int t = 0; t <= T; ++t) {
        if (t == T && have_hist) break;   // tail iter only for in-loop dot

        u32t* xc = bufs[t & 1];
        const u64t tg = (u64t)(u32t)t;
        const float ut = (t < T) ? u[t] : 0.0f;

        // ---- poll own 4 contiguous words (2 x 8B), predicated + throttled ----
        const u64t* p = (const u64t*)xc + 2 * tid;
        u64t a = xload64(p);
        u64t b = xload64(p + 1);
        for (;;) {
            bool okA = (((a >> 16) & 0xFFFFull) == tg) && ((a >> 48) == tg);
            bool okB = (((b >> 16) & 0xFFFFull) == tg) && ((b >> 48) == tg);
            if (okA && okB) break;
            __builtin_amdgcn_s_sleep(1);
            if (!okA) a = xload64(p);
            if (!okB) b = xload64(p + 1);
        }
        ((float4*)xs)[tid] = make_float4(
            h2f((unsigned short)(a & 0xFFFF)),
            h2f((unsigned short)((a >> 32) & 0xFFFF)),
            h2f((unsigned short)(b & 0xFFFF)),
            h2f((unsigned short)((b >> 32) & 0xFFFF)));
        __syncthreads();

        // ---- half-row gather: 8 nnz per lane ----
        if (t < T) {
            float acc = 0.0f;
            acc += rv0.x * xs[rc0.x]; acc += rv0.y * xs[rc0.y];
            acc += rv0.z * xs[rc0.z]; acc += rv0.w * xs[rc0.w];
            acc += rv1.x * xs[rc1.x]; acc += rv1.y * xs[rc1.y];
            acc += rv1.z * xs[rc1.z]; acc += rv1.w * xs[rc1.w];
            #pragma unroll
            for (int off = 32; off > 0; off >>= 1)
                acc += __shfl_xor(acc, off, 64);
            if (lane == 0) hpart[wave] = acc;
        }

        // ---- fallback in-loop output dot (no hist buffer) ----
        const bool des = (!have_hist) && (t >= WASHOUT_N + 1) &&
                         ((t & (NBLOCKS - 1)) == (int)blockIdx.x);
        if (des) {
            float d = we0 * xs[tid] + we1 * xs[TPB + tid]
                    + we2 * xs[2 * TPB + tid] + we3 * xs[3 * TPB + tid];
            #pragma unroll
            for (int off = 32; off > 0; off >>= 1)
                d += __shfl_xor(d, off, 64);
            if (lane == 0) dpart[wave] = d;
        }
        __syncthreads();

        // ---- wave 0: combine halves, tanh, ONE coalesced 32B publish ----
        if (wave == 0) {
            if (t < T && lane < ROWS_PER_BLOCK) {
                float s = hpart[2 * lane] + hpart[2 * lane + 1];
                float z = __fmaf_rn(wi_pub, ut, s);
                float e = __expf(2.0f * z);               // tanh via exp
                float xnew = 1.0f - 2.0f / (e + 1.0f);
                u32t w = ((u32t)(t + 1) << 16) | (u32t)f2h(xnew);
                __hip_atomic_store(&bufs[(t + 1) & 1][base_row + lane], w,
                                   __ATOMIC_RELAXED, __HIP_MEMORY_SCOPE_AGENT);
                if (have_hist)
                    hist[(size_t)t * Nn + base_row + lane] =
                        (unsigned short)(w & 0xFFFF);
            }
            if (des) {
                float s = (lane < NWAVES) ? dpart[lane] : 0.0f;
                #pragma unroll
                for (int off = 8; off > 0; off >>= 1)
                    s += __shfl_xor(s, off, 64);
                if (lane == 0) out[t - WASHOUT_N - 1] = s;
            }
        }
    }
}

// out[k] = dot(w_eff, hist[k + WASHOUT_N])  -- one block per output element
__global__ __launch_bounds__(256) void esn_out_gemv(
    const unsigned short* __restrict__ hist, const float* __restrict__ w_eff,
    float* __restrict__ out, int n_out)
{
    __shared__ float swave[4];
    int k = blockIdx.x;
    if (k >= n_out) return;
    const __half2* hp = (const __half2*)(hist + (size_t)(k + WASHOUT_N) * Nn);
    const int tid = threadIdx.x;
    float acc = 0.0f;
    #pragma unroll
    for (int j = tid; j < Nn / 2; j += 256) {
        float2 xv = __half22float2(hp[j]);
        acc += w_eff[2 * j] * xv.x + w_eff[2 * j + 1] * xv.y;
    }
    #pragma unroll
    for (int off = 32; off > 0; off >>= 1)
        acc += __shfl_xor(acc, off, 64);
    if ((tid & 63) == 0) swave[tid >> 6] = acc;
    __syncthreads();
    if (tid == 0) out[k] = swave[0] + swave[1] + swave[2] + swave[3];
}

extern "C" void kernel_launch(void* const* d_in, const int* in_sizes, int n_in,
                              void* d_out, int out_size, void* d_ws, size_t ws_size,
                              hipStream_t stream)
{
    const float* u     = (const float*)d_in[0];
    const float* W     = (const float*)d_in[1];
    const float* w_in  = (const float*)d_in[2];
    const float* w_out = (const float*)d_in[3];
    const int*   mask  = (const int*)d_in[4];
    float* out = (float*)d_out;
    int T = in_sizes[0];

    const size_t ev_bytes   = (size_t)Nn * ELL_CAP * sizeof(float);          // 16 MB
    const size_t ec_bytes   = (size_t)Nn * ELL_CAP * sizeof(unsigned short); // 8 MB
    const size_t hist_bytes = (size_t)Nn * Nn * sizeof(unsigned short);      // 32 MB
    const size_t aux_bytes  = 64 * 1024;
    char* ws = (char*)d_ws;

    const bool fits_hist =
        ws_size >= ev_bytes + ec_bytes + hist_bytes + aux_bytes;
    const bool fits_ell = ws_size >= ev_bytes + ec_bytes + aux_bytes;

    if (fits_ell) {
        size_t off = 0;
        float*          ev    = (float*)(ws + off);  off += ev_bytes;
        unsigned short* ec    = (unsigned short*)(ws + off);  off += ec_bytes;
        unsigned short* hist  = nullptr;
        if (fits_hist) { hist = (unsigned short*)(ws + off); off += hist_bytes; }
        u32t*           xp_a  = (u32t*)(ws + off);
        u32t*           xp_b  = (u32t*)(ws + off + 16384);
        float*          w_eff = (float*)(ws + off + 32768);

        hipLaunchKernelGGL(esn_init, dim3(16), dim3(256), 0, stream,
                           w_out, mask, xp_a, xp_b, w_eff, out, out_size);
        hipLaunchKernelGGL(build_ell, dim3(Nn), dim3(256), 0, stream, W, ev, ec);

        void* args[] = { (void*)&u, (void*)&w_in, (void*)&ev, (void*)&ec,
                         (void*)&xp_a, (void*)&xp_b, (void*)&w_eff,
                         (void*)&hist, (void*)&out, (void*)&T };
        hipError_t err = hipLaunchCooperativeKernel((const void*)esn_step_sparse,
                                                    dim3(NBLOCKS), dim3(TPB),
                                                    args, 0, stream);
        if (err != hipSuccess) {
            hipLaunchKernelGGL(esn_step_sparse, dim3(NBLOCKS), dim3(TPB), 0, stream,
                               u, w_in, ev, ec, xp_a, xp_b, w_eff, hist, out, T);
        }
        if (fits_hist) {
            hipLaunchKernelGGL(esn_out_gemv, dim3(out_size), dim3(256), 0, stream,
                               hist, w_eff, out, out_size);
        }
    }
}

// Round 9
// 8505.237 us; speedup vs baseline: 2.3014x; 2.3014x over previous
//
#include <hip/hip_runtime.h>
#include <hip/hip_runtime_api.h>
#include <hip/hip_fp16.h>
#include <math.h>

// ESN: x_{t+1} = tanh(w_in * u_t + W @ x_t);  out[t-200] = dot(w_eff, x_{t+1})
//
// R9 = exact R5 champion (9.7 ms: tag16|fp16 self-validating words, relaxed
//      agent atomics, 256 blocks x 16 rows, two barriers/step, xpub funnel,
//      wave-0 coalesced 64B publish, fixed 16-group ELL, sleep(1) poll)
//      + ONE change: row reduction via DPP (VALU pipe) instead of 6 LDS-pipe
//      shuffles. Lane 63 holds the row sum.

#define Nn 4096
#define WASHOUT_N 200
#define NBLOCKS 256
#define TPB 1024
#define ROWS_PER_BLOCK 16   // Nn / NBLOCKS
#define NWAVES 16           // TPB / 64
#define ELL_CAP 1024        // 16 gather groups x 64 lanes; mean nnz 819

typedef unsigned long long u64t;
typedef unsigned int u32t;

static __device__ __forceinline__ unsigned short f2h(float f) {
    __half h = __float2half_rn(f);
    union { __half h; unsigned short u; } cv; cv.h = h; return cv.u;
}
static __device__ __forceinline__ float h2f(unsigned short ub) {
    union { __half h; unsigned short u; } cv; cv.u = ub; return __half2float(cv.h);
}

// x += dpp_mov(x); gfx9 wave64 sum building block (VALU only, lane63 = total)
#define DPP_ADD(x, ctrl, rmask)                                              \
    x += __int_as_float(__builtin_amdgcn_update_dpp(                         \
        0, __float_as_int(x), (ctrl), (rmask), 0xf, true))

__global__ __launch_bounds__(256) void esn_init(
    const float* __restrict__ w_out, const int* __restrict__ mask,
    u32t* __restrict__ xp_a, u32t* __restrict__ xp_b,
    float* __restrict__ w_eff, float* __restrict__ out, int out_n)
{
    int i = blockIdx.x * blockDim.x + threadIdx.x;
    if (i < Nn) {
        xp_a[i] = 0u;            // tag 0 | fp16(0.0) == x_0
        xp_b[i] = 0xFFFF0000u;   // invalid tag (never matches 1..4096)
        w_eff[mask[i]] = w_out[i];
        if (i < out_n) out[i] = 0.0f;
    }
}

// One block per row. Deal nonzeros into 16 gather-groups; each group is one
// wave-wide LDS gather. Keep <=2 cols per LDS bank per group (2-way is free).
__global__ __launch_bounds__(256) void build_ell(
    const float* __restrict__ W, float* __restrict__ ev,
    unsigned short* __restrict__ ec)
{
    int row = blockIdx.x;
    __shared__ unsigned int bank_cnt[32];
    __shared__ unsigned int group_cnt[16];
    if (threadIdx.x < 32) bank_cnt[threadIdx.x] = 0u;
    if (threadIdx.x < 16) group_cnt[threadIdx.x] = 0u;
    __syncthreads();

    const float* wr = W + (size_t)row * Nn;
    size_t base = (size_t)row * ELL_CAP;

    for (int s = threadIdx.x; s < ELL_CAP; s += 256) {
        ev[base + s] = 0.0f;
        ec[base + s] = 0;               // col 0 -> broadcast, free
    }
    __syncthreads();

    for (int j = threadIdx.x; j < Nn; j += 256) {
        float v = wr[j];
        if (v != 0.0f) {
            unsigned int b  = (unsigned int)j & 31u;
            unsigned int jb = atomicAdd(&bank_cnt[b], 1u);
            unsigned int g  = jb & 15u;
            unsigned int s  = 0xFFFFFFFFu;
            for (int tries = 0; tries < 16; ++tries) {
                unsigned int cand = atomicAdd(&group_cnt[g], 1u);
                if (cand < 64u) { s = cand; break; }
                g = (g + 1u) & 15u;
            }
            if (s != 0xFFFFFFFFu) {
                unsigned int i = g >> 2, k = g & 3u;
                unsigned int pos = 4u * (i * 64u + s) + k;
                ev[base + pos] = v;
                ec[base + pos] = (unsigned short)j;
            }
        }
    }
}

__device__ __forceinline__ u64t xload64(const u64t* p) {
    return __hip_atomic_load(p, __ATOMIC_RELAXED, __HIP_MEMORY_SCOPE_AGENT);
}

__global__ __launch_bounds__(TPB) void esn_step_sparse(
    const float* __restrict__ u, const float* __restrict__ w_in,
    const float* __restrict__ ev, const unsigned short* __restrict__ ec,
    u32t* xp_a, u32t* xp_b, const float* __restrict__ w_eff,
    unsigned short* __restrict__ hist, float* __restrict__ out, int T)
{
    __shared__ __align__(16) float xs[Nn];
    __shared__ u32t  xpub[NWAVES];
    __shared__ float dpart[NWAVES];

    const int tid  = threadIdx.x;
    const int lane = tid & 63;
    const int wave = tid >> 6;
    const int base_row = blockIdx.x * ROWS_PER_BLOCK;
    const int row  = base_row + wave;

    const float wi = w_in[row];
    // fallback-dot weights (no-hist path only)
    const float we0 = w_eff[tid];
    const float we1 = w_eff[TPB + tid];
    const float we2 = w_eff[2 * TPB + tid];
    const float we3 = w_eff[3 * TPB + tid];

    // hoist this row's ELL slice into registers (loop-invariant)
    const float4*  v4 = (const float4*)(ev + (size_t)row * ELL_CAP);
    const ushort4* c4 = (const ushort4*)(ec + (size_t)row * ELL_CAP);
    const float4  rv0 = v4[lane],       rv1 = v4[64 + lane],
                  rv2 = v4[128 + lane], rv3 = v4[192 + lane];
    const ushort4 rc0 = c4[lane],       rc1 = c4[64 + lane],
                  rc2 = c4[128 + lane], rc3 = c4[192 + lane];

    u32t* bufs[2] = { xp_a, xp_b };
    const bool have_hist = (hist != nullptr);

    for (int t = 0; t <= T; ++t) {
        if (t == T && have_hist) break;   // tail iter only for in-loop dot

        u32t* xc = bufs[t & 1];
        const u64t tg = (u64t)(u32t)t;
        const float ut = (t < T) ? u[t] : 0.0f;

        // ---- poll own 4 contiguous words (2 x 8B), predicated + throttled ----
        const u64t* p = (const u64t*)xc + 2 * tid;
        u64t a = xload64(p);
        u64t b = xload64(p + 1);
        for (;;) {
            bool okA = (((a >> 16) & 0xFFFFull) == tg) && ((a >> 48) == tg);
            bool okB = (((b >> 16) & 0xFFFFull) == tg) && ((b >> 48) == tg);
            if (okA && okB) break;
            __builtin_amdgcn_s_sleep(1);
            if (!okA) a = xload64(p);
            if (!okB) b = xload64(p + 1);
        }
        // extract fp16 values, stage 4 floats with one ds_write_b128
        ((float4*)xs)[tid] = make_float4(
            h2f((unsigned short)(a & 0xFFFF)),
            h2f((unsigned short)((a >> 32) & 0xFFFF)),
            h2f((unsigned short)(b & 0xFFFF)),
            h2f((unsigned short)((b >> 32) & 0xFFFF)));
        __syncthreads();

        // ---- row update ----
        if (t < T) {
            float acc = 0.0f;
            acc += rv0.x * xs[rc0.x]; acc += rv0.y * xs[rc0.y];
            acc += rv0.z * xs[rc0.z]; acc += rv0.w * xs[rc0.w];
            acc += rv1.x * xs[rc1.x]; acc += rv1.y * xs[rc1.y];
            acc += rv1.z * xs[rc1.z]; acc += rv1.w * xs[rc1.w];
            acc += rv2.x * xs[rc2.x]; acc += rv2.y * xs[rc2.y];
            acc += rv2.z * xs[rc2.z]; acc += rv2.w * xs[rc2.w];
            acc += rv3.x * xs[rc3.x]; acc += rv3.y * xs[rc3.y];
            acc += rv3.z * xs[rc3.z]; acc += rv3.w * xs[rc3.w];

            // wave64 sum via DPP (VALU pipe; lane 63 ends with the total)
            DPP_ADD(acc, 0x111, 0xf);   // row_shr:1
            DPP_ADD(acc, 0x112, 0xf);   // row_shr:2
            DPP_ADD(acc, 0x114, 0xf);   // row_shr:4
            DPP_ADD(acc, 0x118, 0xf);   // row_shr:8
            DPP_ADD(acc, 0x142, 0xa);   // row_bcast:15 -> rows 1,3
            DPP_ADD(acc, 0x143, 0xc);   // row_bcast:31 -> rows 2,3

            if (lane == 63) {
                float z = __fmaf_rn(wi, ut, acc);
                float e = __expf(2.0f * z);               // tanh via exp
                float xnew = 1.0f - 2.0f / (e + 1.0f);
                xpub[wave] = ((u32t)(t + 1) << 16) | (u32t)f2h(xnew);
            }
        }

        // ---- fallback in-loop output dot (no hist buffer) ----
        const bool des = (!have_hist) && (t >= WASHOUT_N + 1) &&
                         ((t & (NBLOCKS - 1)) == (int)blockIdx.x);
        if (des) {
            float d = we0 * xs[tid] + we1 * xs[TPB + tid]
                    + we2 * xs[2 * TPB + tid] + we3 * xs[3 * TPB + tid];
            #pragma unroll
            for (int off = 32; off > 0; off >>= 1)
                d += __shfl_xor(d, off, 64);
            if (lane == 0) dpart[wave] = d;
        }
        __syncthreads();

        // ---- coalesced publish by wave 0 (one 64B line) + hist append ----
        if (wave == 0) {
            if (t < T && lane < ROWS_PER_BLOCK) {
                u32t w = xpub[lane];
                __hip_atomic_store(&bufs[(t + 1) & 1][base_row + lane], w,
                                   __ATOMIC_RELAXED, __HIP_MEMORY_SCOPE_AGENT);
                if (have_hist)
                    hist[(size_t)t * Nn + base_row + lane] =
                        (unsigned short)(w & 0xFFFF);
            }
            if (des) {
                float s = (lane < NWAVES) ? dpart[lane] : 0.0f;
                #pragma unroll
                for (int off = 8; off > 0; off >>= 1)
                    s += __shfl_xor(s, off, 64);
                if (lane == 0) out[t - WASHOUT_N - 1] = s;
            }
        }
        // no trailing barrier needed: staging for t+1 only writes each
        // thread's own chunk, and all gathers from xs precede the barrier
        // above in program order.
    }
}

// out[k] = dot(w_eff, hist[k + WASHOUT_N])  -- one block per output element
__global__ __launch_bounds__(256) void esn_out_gemv(
    const unsigned short* __restrict__ hist, const float* __restrict__ w_eff,
    float* __restrict__ out, int n_out)
{
    __shared__ float swave[4];
    int k = blockIdx.x;
    if (k >= n_out) return;
    const __half2* hp = (const __half2*)(hist + (size_t)(k + WASHOUT_N) * Nn);
    const int tid = threadIdx.x;
    float acc = 0.0f;
    #pragma unroll
    for (int j = tid; j < Nn / 2; j += 256) {
        float2 xv = __half22float2(hp[j]);
        acc += w_eff[2 * j] * xv.x + w_eff[2 * j + 1] * xv.y;
    }
    #pragma unroll
    for (int off = 32; off > 0; off >>= 1)
        acc += __shfl_xor(acc, off, 64);
    if ((tid & 63) == 0) swave[tid >> 6] = acc;
    __syncthreads();
    if (tid == 0) out[k] = swave[0] + swave[1] + swave[2] + swave[3];
}

extern "C" void kernel_launch(void* const* d_in, const int* in_sizes, int n_in,
                              void* d_out, int out_size, void* d_ws, size_t ws_size,
                              hipStream_t stream)
{
    const float* u     = (const float*)d_in[0];
    const float* W     = (const float*)d_in[1];
    const float* w_in  = (const float*)d_in[2];
    const float* w_out = (const float*)d_in[3];
    const int*   mask  = (const int*)d_in[4];
    float* out = (float*)d_out;
    int T = in_sizes[0];

    const size_t ev_bytes   = (size_t)Nn * ELL_CAP * sizeof(float);          // 16 MB
    const size_t ec_bytes   = (size_t)Nn * ELL_CAP * sizeof(unsigned short); // 8 MB
    const size_t hist_bytes = (size_t)Nn * Nn * sizeof(unsigned short);      // 32 MB
    const size_t aux_bytes  = 64 * 1024;
    char* ws = (char*)d_ws;

    const bool fits_hist =
        ws_size >= ev_bytes + ec_bytes + hist_bytes + aux_bytes;
    const bool fits_ell = ws_size >= ev_bytes + ec_bytes + aux_bytes;

    if (fits_ell) {
        size_t off = 0;
        float*          ev    = (float*)(ws + off);  off += ev_bytes;
        unsigned short* ec    = (unsigned short*)(ws + off);  off += ec_bytes;
        unsigned short* hist  = nullptr;
        if (fits_hist) { hist = (unsigned short*)(ws + off); off += hist_bytes; }
        u32t*           xp_a  = (u32t*)(ws + off);
        u32t*           xp_b  = (u32t*)(ws + off + 16384);
        float*          w_eff = (float*)(ws + off + 32768);

        hipLaunchKernelGGL(esn_init, dim3(16), dim3(256), 0, stream,
                           w_out, mask, xp_a, xp_b, w_eff, out, out_size);
        hipLaunchKernelGGL(build_ell, dim3(Nn), dim3(256), 0, stream, W, ev, ec);

        void* args[] = { (void*)&u, (void*)&w_in, (void*)&ev, (void*)&ec,
                         (void*)&xp_a, (void*)&xp_b, (void*)&w_eff,
                         (void*)&hist, (void*)&out, (void*)&T };
        hipError_t err = hipLaunchCooperativeKernel((const void*)esn_step_sparse,
                                                    dim3(NBLOCKS), dim3(TPB),
                                                    args, 0, stream);
        if (err != hipSuccess) {
            hipLaunchKernelGGL(esn_step_sparse, dim3(NBLOCKS), dim3(TPB), 0, stream,
                               u, w_in, ev, ec, xp_a, xp_b, w_eff, hist, out, T);
        }
        if (fits_hist) {
            hipLaunchKernelGGL(esn_out_gemv, dim3(out_size), dim3(256), 0, stream,
                               hist, w_eff, out, out_size);
        }
    }
}